// Round 1
// baseline (58.354 us; speedup 1.0000x reference)
//
#include <hip/hip_runtime.h>

// Problem dims (fixed by reference)
constexpr int T = 64, B = 8, A = 3, S = 400, V = 50000, N_OOV = 400;
constexpr int V_EXT = V + N_OOV;

// One block per (t,b). Phase 1: out[v<V] = coef * vocab_probs[v], out[V:]=0
// (fully coalesced float4). Phase 2: scatter-add 1200 copy weights via
// atomicAdd into the block's own freshly-written region (L2-resident).
__global__ __launch_bounds__(1024) void pg_mix_kernel(
    const int*   __restrict__ article,        // [S,B,A]
    const float* __restrict__ vocab_probs,    // [T,B,V]
    const float* __restrict__ gen_probs,      // [T,B,A]
    const float* __restrict__ agentwise_attn, // [T,B,A,S]
    const float* __restrict__ agent_attn,     // [T,B,A]
    float*       __restrict__ out)            // [T,B,V_EXT]
{
    const int tb  = blockIdx.x;           // t*B + b
    const int b   = tb % B;
    const int tid = threadIdx.x;
    const int nth = blockDim.x;

    // Per-(t,b) scalars: coef = sum_a aa*g ; cw[a] = aa*(1-g)
    float coef = 0.f;
    float cw[A];
#pragma unroll
    for (int a = 0; a < A; ++a) {
        const float aa = agent_attn[tb * A + a];
        const float g  = gen_probs[tb * A + a];
        coef += aa * g;
        cw[a] = aa * (1.f - g);
    }

    const float4* vp4  = reinterpret_cast<const float4*>(vocab_probs + (size_t)tb * V);
    float4*       out4 = reinterpret_cast<float4*>(out + (size_t)tb * V_EXT);

    // Base vocab: scaled stream (V/4 = 12500 float4 per block)
    for (int i = tid; i < V / 4; i += nth) {
        float4 v = vp4[i];
        v.x *= coef; v.y *= coef; v.z *= coef; v.w *= coef;
        out4[i] = v;
    }
    // OOV tail: zero (100 float4)
    for (int i = V / 4 + tid; i < V_EXT / 4; i += nth) {
        out4[i] = make_float4(0.f, 0.f, 0.f, 0.f);
    }

    __syncthreads();  // drains vmcnt(0): stores visible in L2 before atomics

    // Scatter: A*S = 1200 contributions into this block's region
    float* outp = out + (size_t)tb * V_EXT;
    for (int i = tid; i < A * S; i += nth) {
        const int a = i / S;
        const int s = i - a * S;
        const float w   = cw[a] * agentwise_attn[((size_t)tb * A + a) * S + s];
        const int   idx = article[(s * B + b) * A + a];
        atomicAdd(outp + idx, w);
    }
}

extern "C" void kernel_launch(void* const* d_in, const int* in_sizes, int n_in,
                              void* d_out, int out_size, void* d_ws, size_t ws_size,
                              hipStream_t stream) {
    const int*   article        = (const int*)  d_in[0]; // [S,B,A]
    const float* vocab_probs    = (const float*)d_in[1]; // [T,B,V]
    const float* gen_probs      = (const float*)d_in[2]; // [T,B,A]
    const float* agentwise_attn = (const float*)d_in[3]; // [T,B,A,S]
    const float* agent_attn     = (const float*)d_in[4]; // [T,B,A]
    float*       out            = (float*)d_out;         // [T,B,V_EXT]

    dim3 grid(T * B);   // 512 blocks
    dim3 block(1024);   // 16 waves/block -> 32 waves/CU at 2 blocks/CU
    pg_mix_kernel<<<grid, block, 0, stream>>>(article, vocab_probs, gen_probs,
                                              agentwise_attn, agent_attn, out);
}